// Round 13
// baseline (197.947 us; speedup 1.0000x reference)
//
#include <hip/hip_runtime.h>
#include <hip/hip_bf16.h>

typedef __attribute__((ext_vector_type(8))) short bf16x8;
typedef __attribute__((ext_vector_type(4))) float f32x4;
typedef __attribute__((ext_vector_type(4))) unsigned u32x4;

#define T_LEN 2048
#define S_ENC 256
#define QSCALE 0.18033688011112042f     // 64^-0.5 * log2(e): softmax in log2 domain
#define BARRIER() __syncthreads()

__device__ __forceinline__ float exp2_hw(float x) {
#if __has_builtin(__builtin_amdgcn_exp2f)
  return __builtin_amdgcn_exp2f(x);
#else
  float r;
  asm("v_exp_f32 %0, %1" : "=v"(r) : "v"(x));
  return r;
#endif
}

// hardware packed f32->bf16 (RNE), 2 values per instruction
__device__ __forceinline__ unsigned cvt_pk_bf16(float lo, float hi) {
  unsigned r;
  asm("v_cvt_pk_bf16_f32 %0, %1, %2" : "=v"(r) : "v"(lo), "v"(hi));
  return r;
}

__device__ __forceinline__ short f2bf(float x) {   // cold path (Q frag) only
  union { __hip_bfloat16 b; short s; } u;
  u.b = __float2bfloat16(x);
  return u.s;
}

// XOR bank swizzle (T2, verified: conflicts 9.4M -> 0): rows of 64 shorts
// (128B), 16B-slot index ^= row&7. Applied on BOTH write and read sides.
__device__ __forceinline__ int swz(int row, int col) {
  return row * 64 + (col ^ ((row & 7) << 3));
}

union PU { u32x4 u; bf16x8 b; };

// ---- K-only staging (R9-verbatim K path; V no longer staged) ----
template<int STRIDE>
__device__ __forceinline__ void issue_loads(
    const float* __restrict__ kb, int s0, int tid,
    float (&kr)[8], float (&kr2)[8]) {
  const int ks = tid & 63;
  const int kc = (tid >> 6) * 8;
  const float* kp = kb + (size_t)kc * STRIDE + (s0 + ks);
  const float* kp2 = kp + (size_t)32 * STRIDE;
#pragma unroll
  for (int r = 0; r < 8; ++r) kr[r] = kp[(size_t)r * STRIDE];
#pragma unroll
  for (int r = 0; r < 8; ++r) kr2[r] = kp2[(size_t)r * STRIDE];
}

__device__ __forceinline__ void stage_write(
    short* __restrict__ Kt, int tid,
    const float (&kr)[8], const float (&kr2)[8]) {
  const int ks = tid & 63;
  const int kc = (tid >> 6) * 8;
  u32x4 kw;
#pragma unroll
  for (int r = 0; r < 4; ++r) kw[r] = cvt_pk_bf16(kr[2 * r], kr[2 * r + 1]);
  *(u32x4*)(Kt + swz(ks, kc)) = kw;
  u32x4 kw2;
#pragma unroll
  for (int r = 0; r < 4; ++r) kw2[r] = cvt_pk_bf16(kr2[2 * r], kr2[2 * r + 1]);
  *(u32x4*)(Kt + swz(ks, kc + 32)) = kw2;
}

// ---- compute: K from LDS (R9 verbatim), V DIRECT from global (L2-hot).
// vf key mapping preserved exactly: vf.b[j] = V[16ct+ln][s0+32sub+4lg+16*(j>>2)+(j&3)]
// == the sigma-permuted-LDS path's values, bit for bit.
template<int STRIDE>
__device__ __forceinline__ void compute_tile(
    const short* __restrict__ Kt, const float* __restrict__ vt /* vb + s0 */,
    const bf16x8 (&qf)[4][2], f32x4 (&o)[4][4], float (&lp)[4], int tid) {
  const int lane = tid & 63;
  const int ln = lane & 15;
  const int lg = lane >> 4;

  // ---- issue V sub0 loads early: L2 latency hides under QK pair0 ----
  f32x4 va[4], vb_[4], vc_[4], vd[4];   // [ct]: sub0 lo/hi, sub1 lo/hi
#pragma unroll
  for (int ct = 0; ct < 4; ++ct) {
    const float* p = vt + (size_t)(16 * ct + ln) * STRIDE + 4 * lg;
    va[ct] = *(const f32x4*)p;
    vb_[ct] = *(const f32x4*)(p + 16);
  }

  bf16x8 kf[4][2];
#pragma unroll
  for (int mt = 0; mt < 4; ++mt) {
    const int row = 16 * mt + ln;
    kf[mt][0] = *(const bf16x8*)(Kt + swz(row, 8 * lg));
    kf[mt][1] = *(const bf16x8*)(Kt + swz(row, 32 + 8 * lg));
  }

  PU pfrag[4][2];
#pragma unroll
  for (int pr = 0; pr < 2; ++pr) {
    f32x4 sacc[2][4];
#pragma unroll
    for (int q2 = 0; q2 < 2; ++q2)
#pragma unroll
      for (int mt = 0; mt < 4; ++mt) sacc[q2][mt] = (f32x4){0.f, 0.f, 0.f, 0.f};

#pragma unroll
    for (int mt = 0; mt < 4; ++mt)
#pragma unroll
      for (int q2 = 0; q2 < 2; ++q2) {
        const int qt = 2 * pr + q2;
        sacc[q2][mt] = __builtin_amdgcn_mfma_f32_16x16x32_bf16(kf[mt][0], qf[qt][0], sacc[q2][mt], 0, 0, 0);
        sacc[q2][mt] = __builtin_amdgcn_mfma_f32_16x16x32_bf16(kf[mt][1], qf[qt][1], sacc[q2][mt], 0, 0, 0);
      }

    if (pr == 0) {
      // issue V sub1 loads: latency hidden under sm pair0 + QK pair1
#pragma unroll
      for (int ct = 0; ct < 4; ++ct) {
        const float* p = vt + (size_t)(16 * ct + ln) * STRIDE + 32 + 4 * lg;
        vc_[ct] = *(const f32x4*)p;
        vd[ct] = *(const f32x4*)(p + 16);
      }
    }

#pragma unroll
    for (int q2 = 0; q2 < 2; ++q2) {
      const int qt = 2 * pr + q2;
      float pmt[4];
#pragma unroll
      for (int mt = 0; mt < 4; ++mt) {
        float p0 = exp2_hw(sacc[q2][mt][0]);
        float p1 = exp2_hw(sacc[q2][mt][1]);
        float p2 = exp2_hw(sacc[q2][mt][2]);
        float p3 = exp2_hw(sacc[q2][mt][3]);
        pfrag[qt][mt >> 1].u[2 * (mt & 1) + 0] = cvt_pk_bf16(p0, p1);
        pfrag[qt][mt >> 1].u[2 * (mt & 1) + 1] = cvt_pk_bf16(p2, p3);
        pmt[mt] = (p0 + p1) + (p2 + p3);
      }
      lp[qt] += (pmt[0] + pmt[1]) + (pmt[2] + pmt[3]);
    }
  }

  // ---- O^T += V * P^T : vf built in-register from global V (cvt_pk RNE) ----
#pragma unroll
  for (int sub = 0; sub < 2; ++sub)
#pragma unroll
    for (int ct = 0; ct < 4; ++ct) {
      const f32x4 lo = sub ? vc_[ct] : va[ct];
      const f32x4 hi = sub ? vd[ct] : vb_[ct];
      PU vf;
      vf.u[0] = cvt_pk_bf16(lo[0], lo[1]);
      vf.u[1] = cvt_pk_bf16(lo[2], lo[3]);
      vf.u[2] = cvt_pk_bf16(hi[0], hi[1]);
      vf.u[3] = cvt_pk_bf16(hi[2], hi[3]);
#pragma unroll
      for (int qt = 0; qt < 4; ++qt)
        o[qt][ct] = __builtin_amdgcn_mfma_f32_16x16x32_bf16(vf.b, pfrag[qt][sub].b, o[qt][ct], 0, 0, 0);
    }
}

__global__ __launch_bounds__(256, 2) void attn_kernel(
    const float* __restrict__ qkv, const float* __restrict__ ekv,
    float* __restrict__ out) {
  const int tid = threadIdx.x;
  const int lane = tid & 63;
  const int wave = tid >> 6;              // 0..3
  const int ln = lane & 15;
  const int lg = lane >> 4;

  // XCD swizzle (verified: FETCH 315->74 MB): all 8 q-blocks of one head
  // land on the same XCD (blk%8 == bh%8 for all of them)
  const int bh = blockIdx.x & 63;
  const int qb = blockIdx.x >> 6;         // 0..7
  const int t0 = qb * 256 + wave * 64;    // this wave: queries t0 .. t0+63

  const float* qp  = qkv + (size_t)bh * 192 * T_LEN;
  const float* kp  = qp + (size_t)64 * T_LEN;
  const float* vp  = qp + (size_t)128 * T_LEN;
  const float* ekp = ekv + (size_t)bh * 128 * S_ENC;
  const float* evp = ekp + (size_t)64 * S_ENC;

  __shared__ __attribute__((aligned(16))) short Kt[64 * 64];   // K only: 8 KB

  // Q fragments (channel mapping 32*kk + 8*lg + j, matching K-frag reads)
  bf16x8 qf[4][2];
#pragma unroll
  for (int qt = 0; qt < 4; ++qt)
#pragma unroll
    for (int kk = 0; kk < 2; ++kk)
#pragma unroll
      for (int j = 0; j < 8; ++j)
        qf[qt][kk][j] =
            f2bf(qp[(size_t)(32 * kk + 8 * lg + j) * T_LEN + (t0 + 16 * qt + ln)] * QSCALE);

  f32x4 o[4][4];
#pragma unroll
  for (int qt = 0; qt < 4; ++qt)
#pragma unroll
    for (int ct = 0; ct < 4; ++ct) o[qt][ct] = (f32x4){0.f, 0.f, 0.f, 0.f};
  float lp[4] = {0.f, 0.f, 0.f, 0.f};

  for (int st = 0; st < 4; ++st) {
    float kr[8], kr2[8];
    issue_loads<S_ENC>(ekp, 64 * st, tid, kr, kr2);
    BARRIER();   // prior tile's K LDS reads complete
    stage_write(Kt, tid, kr, kr2);
    BARRIER();   // K tile staged
    compute_tile<S_ENC>(Kt, evp + 64 * st, qf, o, lp, tid);
  }
  for (int st = 0; st < 32; ++st) {
    float kr[8], kr2[8];
    issue_loads<T_LEN>(kp, 64 * st, tid, kr, kr2);
    BARRIER();
    stage_write(Kt, tid, kr, kr2);
    BARRIER();
    compute_tile<T_LEN>(Kt, vp + 64 * st, qf, o, lp, tid);
  }

  // ---- epilogue: reduce l across the 4 lane-groups, normalize, store O^T ----
#pragma unroll
  for (int qt = 0; qt < 4; ++qt) {
    float l = lp[qt];
    l += __shfl_xor(l, 16);
    l += __shfl_xor(l, 32);
    const float inv = 1.0f / l;
    float* ob = out + (size_t)bh * 64 * T_LEN + (t0 + 16 * qt + ln);
#pragma unroll
    for (int ct = 0; ct < 4; ++ct)
#pragma unroll
      for (int r = 0; r < 4; ++r)
        ob[(size_t)(16 * ct + 4 * lg + r) * T_LEN] = o[qt][ct][r] * inv;
  }
}

extern "C" void kernel_launch(void* const* d_in, const int* in_sizes, int n_in,
                              void* d_out, int out_size, void* d_ws, size_t ws_size,
                              hipStream_t stream) {
  const float* qkv = (const float*)d_in[0];
  const float* ekv = (const float*)d_in[1];
  float* out = (float*)d_out;
  attn_kernel<<<dim3(512), dim3(256), 0, stream>>>(qkv, ekv, out);
}

// Round 14
// 93.217 us; speedup vs baseline: 2.1235x; 2.1235x over previous
//
#include <hip/hip_runtime.h>
#include <hip/hip_bf16.h>

typedef __attribute__((ext_vector_type(8))) short bf16x8;
typedef __attribute__((ext_vector_type(4))) float f32x4;
typedef __attribute__((ext_vector_type(4))) unsigned u32x4;
typedef __attribute__((ext_vector_type(2))) unsigned u32x2;

#define T_LEN 2048
#define S_ENC 256
#define QSCALE 0.18033688011112042f     // 64^-0.5 * log2(e): softmax in log2 domain
#define BARRIER() __syncthreads()

__device__ __forceinline__ float exp2_hw(float x) {
#if __has_builtin(__builtin_amdgcn_exp2f)
  return __builtin_amdgcn_exp2f(x);
#else
  float r;
  asm("v_exp_f32 %0, %1" : "=v"(r) : "v"(x));
  return r;
#endif
}

// hardware packed f32->bf16 (RNE), 2 values per instruction
__device__ __forceinline__ unsigned cvt_pk_bf16(float lo, float hi) {
  unsigned r;
  asm("v_cvt_pk_bf16_f32 %0, %1, %2" : "=v"(r) : "v"(lo), "v"(hi));
  return r;
}

__device__ __forceinline__ short f2bf(float x) {   // cold path (Q frag) only
  union { __hip_bfloat16 b; short s; } u;
  u.b = __float2bfloat16(x);
  return u.s;
}

// XOR bank swizzle (T2, verified: conflicts 9.4M -> 0): rows of 64 shorts
// (128B), 16B-slot index ^= row&7. Applied on BOTH write and read sides.
__device__ __forceinline__ int swz(int row, int col) {
  return row * 64 + (col ^ ((row & 7) << 3));
}

union PU { u32x4 u; bf16x8 b; };

// ---- staging (R9-verbatim index math) ----
template<int STRIDE>
__device__ __forceinline__ void issue_loads(
    const float* __restrict__ kb, const float* __restrict__ vb, int s0, int tid,
    float (&kr)[8], float (&kr2)[8], f32x4 (&vr)[4]) {
  const int ks = tid & 63;
  const int kc = (tid >> 6) * 8;
  const float* kp = kb + (size_t)kc * STRIDE + (s0 + ks);
  const float* kp2 = kp + (size_t)32 * STRIDE;
#pragma unroll
  for (int r = 0; r < 8; ++r) kr[r] = kp[(size_t)r * STRIDE];
#pragma unroll
  for (int r = 0; r < 8; ++r) kr2[r] = kp2[(size_t)r * STRIDE];
  const int vg = tid & 15;
  const int vc = tid >> 4;
  const float* vp0 = vb + (size_t)vc * STRIDE + (s0 + 4 * vg);
  vr[0] = *(const f32x4*)(vp0);
  vr[1] = *(const f32x4*)(vp0 + (size_t)32 * STRIDE);
  vr[2] = *(const f32x4*)(vp0 + (size_t)16 * STRIDE);
  vr[3] = *(const f32x4*)(vp0 + (size_t)48 * STRIDE);
}

__device__ __forceinline__ void stage_write(
    short* __restrict__ Kt, short* __restrict__ Vt, int tid,
    const float (&kr)[8], const float (&kr2)[8], const f32x4 (&vr)[4]) {
  const int ks = tid & 63;
  const int kc = (tid >> 6) * 8;
  u32x4 kw;
#pragma unroll
  for (int r = 0; r < 4; ++r) kw[r] = cvt_pk_bf16(kr[2 * r], kr[2 * r + 1]);
  *(u32x4*)(Kt + swz(ks, kc)) = kw;
  u32x4 kw2;
#pragma unroll
  for (int r = 0; r < 4; ++r) kw2[r] = cvt_pk_bf16(kr2[2 * r], kr2[2 * r + 1]);
  *(u32x4*)(Kt + swz(ks, kc + 32)) = kw2;

  const int vg = tid & 15;
  const int vc = tid >> 4;
  const int vcol = 32 * (vg >> 3) + 8 * (vg & 3) + 4 * ((vg >> 2) & 1);  // sigma-perm
  const int vrow[4] = {vc, vc + 32, vc + 16, vc + 48};
#pragma unroll
  for (int i = 0; i < 4; ++i) {
    u32x2 vw;
    vw[0] = cvt_pk_bf16(vr[i][0], vr[i][1]);
    vw[1] = cvt_pk_bf16(vr[i][2], vr[i][3]);
    *(u32x2*)(Vt + swz(vrow[i], vcol)) = vw;
  }
}

// ---- compute (R9 verbatim + T5 setprio around MFMA clusters) ----
__device__ __forceinline__ void compute_tile(
    const short* __restrict__ Kt, const short* __restrict__ Vt,
    const bf16x8 (&qf)[4][2], f32x4 (&o)[4][4], float (&lp)[4], int tid) {
  const int lane = tid & 63;
  const int ln = lane & 15;
  const int lg = lane >> 4;

  bf16x8 kf[4][2];
#pragma unroll
  for (int mt = 0; mt < 4; ++mt) {
    const int row = 16 * mt + ln;
    kf[mt][0] = *(const bf16x8*)(Kt + swz(row, 8 * lg));
    kf[mt][1] = *(const bf16x8*)(Kt + swz(row, 32 + 8 * lg));
  }

  PU pfrag[4][2];
#pragma unroll
  for (int pr = 0; pr < 2; ++pr) {
    f32x4 sacc[2][4];
#pragma unroll
    for (int q2 = 0; q2 < 2; ++q2)
#pragma unroll
      for (int mt = 0; mt < 4; ++mt) sacc[q2][mt] = (f32x4){0.f, 0.f, 0.f, 0.f};

    __builtin_amdgcn_s_setprio(1);
#pragma unroll
    for (int mt = 0; mt < 4; ++mt)
#pragma unroll
      for (int q2 = 0; q2 < 2; ++q2) {
        const int qt = 2 * pr + q2;
        sacc[q2][mt] = __builtin_amdgcn_mfma_f32_16x16x32_bf16(kf[mt][0], qf[qt][0], sacc[q2][mt], 0, 0, 0);
        sacc[q2][mt] = __builtin_amdgcn_mfma_f32_16x16x32_bf16(kf[mt][1], qf[qt][1], sacc[q2][mt], 0, 0, 0);
      }
    __builtin_amdgcn_s_setprio(0);

#pragma unroll
    for (int q2 = 0; q2 < 2; ++q2) {
      const int qt = 2 * pr + q2;
      float pmt[4];
#pragma unroll
      for (int mt = 0; mt < 4; ++mt) {
        float p0 = exp2_hw(sacc[q2][mt][0]);
        float p1 = exp2_hw(sacc[q2][mt][1]);
        float p2 = exp2_hw(sacc[q2][mt][2]);
        float p3 = exp2_hw(sacc[q2][mt][3]);
        pfrag[qt][mt >> 1].u[2 * (mt & 1) + 0] = cvt_pk_bf16(p0, p1);
        pfrag[qt][mt >> 1].u[2 * (mt & 1) + 1] = cvt_pk_bf16(p2, p3);
        pmt[mt] = (p0 + p1) + (p2 + p3);
      }
      lp[qt] += (pmt[0] + pmt[1]) + (pmt[2] + pmt[3]);
    }
  }

  __builtin_amdgcn_s_setprio(1);
#pragma unroll
  for (int sub = 0; sub < 2; ++sub)
#pragma unroll
    for (int ct = 0; ct < 4; ++ct) {
      const bf16x8 vf = *(const bf16x8*)(Vt + swz(16 * ct + ln, 32 * sub + 8 * lg));
#pragma unroll
      for (int qt = 0; qt < 4; ++qt)
        o[qt][ct] = __builtin_amdgcn_mfma_f32_16x16x32_bf16(vf, pfrag[qt][sub].b, o[qt][ct], 0, 0, 0);
    }
  __builtin_amdgcn_s_setprio(0);
}

__global__ __launch_bounds__(256, 2) void attn_kernel(
    const float* __restrict__ qkv, const float* __restrict__ ekv,
    float* __restrict__ out) {
  const int tid = threadIdx.x;
  const int lane = tid & 63;
  const int wave = tid >> 6;              // 0..3
  const int ln = lane & 15;
  const int lg = lane >> 4;

  // XCD swizzle (verified: FETCH 315->74 MB): all 8 q-blocks of one head
  // land on the same XCD (blk%8 == bh%8 for all of them)
  const int bh = blockIdx.x & 63;
  const int qb = blockIdx.x >> 6;         // 0..7
  const int t0 = qb * 256 + wave * 64;    // this wave: queries t0 .. t0+63

  const float* qp  = qkv + (size_t)bh * 192 * T_LEN;
  const float* kp  = qp + (size_t)64 * T_LEN;
  const float* vp  = qp + (size_t)128 * T_LEN;
  const float* ekp = ekv + (size_t)bh * 128 * S_ENC;
  const float* evp = ekp + (size_t)64 * S_ENC;

  // two 64-key sub-tiles staged per barrier pair: 2 x (8 KB K + 8 KB V) = 32 KB
  __shared__ __attribute__((aligned(16))) short Kt[2][64 * 64];
  __shared__ __attribute__((aligned(16))) short Vt[2][64 * 64];

  // Q fragments (channel mapping 32*kk + 8*lg + j, matching K-frag reads)
  bf16x8 qf[4][2];
#pragma unroll
  for (int qt = 0; qt < 4; ++qt)
#pragma unroll
    for (int kk = 0; kk < 2; ++kk)
#pragma unroll
      for (int j = 0; j < 8; ++j)
        qf[qt][kk][j] =
            f2bf(qp[(size_t)(32 * kk + 8 * lg + j) * T_LEN + (t0 + 16 * qt + ln)] * QSCALE);

  f32x4 o[4][4];
#pragma unroll
  for (int qt = 0; qt < 4; ++qt)
#pragma unroll
    for (int ct = 0; ct < 4; ++ct) o[qt][ct] = (f32x4){0.f, 0.f, 0.f, 0.f};
  float lp[4] = {0.f, 0.f, 0.f, 0.f};

  // ---- encoder: 256 keys = 2 batches of 128 (2 x 64-key sub-tiles each) ----
  for (int st = 0; st < 2; ++st) {
    float krA[8], kr2A[8], krB[8], kr2B[8];
    f32x4 vrA[4], vrB[4];
    issue_loads<S_ENC>(ekp, evp, 128 * st, tid, krA, kr2A, vrA);
    issue_loads<S_ENC>(ekp, evp, 128 * st + 64, tid, krB, kr2B, vrB);
    BARRIER();   // prior batch's LDS reads complete
    stage_write(&Kt[0][0], &Vt[0][0], tid, krA, kr2A, vrA);
    stage_write(&Kt[1][0], &Vt[1][0], tid, krB, kr2B, vrB);
    BARRIER();   // batch staged
    compute_tile(&Kt[0][0], &Vt[0][0], qf, o, lp, tid);
    compute_tile(&Kt[1][0], &Vt[1][0], qf, o, lp, tid);
  }
  // ---- self: 2048 keys = 16 batches of 128 ----
  for (int st = 0; st < 16; ++st) {
    float krA[8], kr2A[8], krB[8], kr2B[8];
    f32x4 vrA[4], vrB[4];
    issue_loads<T_LEN>(kp, vp, 128 * st, tid, krA, kr2A, vrA);
    issue_loads<T_LEN>(kp, vp, 128 * st + 64, tid, krB, kr2B, vrB);
    BARRIER();
    stage_write(&Kt[0][0], &Vt[0][0], tid, krA, kr2A, vrA);
    stage_write(&Kt[1][0], &Vt[1][0], tid, krB, kr2B, vrB);
    BARRIER();
    compute_tile(&Kt[0][0], &Vt[0][0], qf, o, lp, tid);
    compute_tile(&Kt[1][0], &Vt[1][0], qf, o, lp, tid);
  }

  // ---- epilogue: reduce l across the 4 lane-groups, normalize, store O^T ----
#pragma unroll
  for (int qt = 0; qt < 4; ++qt) {
    float l = lp[qt];
    l += __shfl_xor(l, 16);
    l += __shfl_xor(l, 32);
    const float inv = 1.0f / l;
    float* ob = out + (size_t)bh * 64 * T_LEN + (t0 + 16 * qt + ln);
#pragma unroll
    for (int ct = 0; ct < 4; ++ct)
#pragma unroll
      for (int r = 0; r < 4; ++r)
        ob[(size_t)(16 * ct + 4 * lg + r) * T_LEN] = o[qt][ct][r] * inv;
  }
}

extern "C" void kernel_launch(void* const* d_in, const int* in_sizes, int n_in,
                              void* d_out, int out_size, void* d_ws, size_t ws_size,
                              hipStream_t stream) {
  const float* qkv = (const float*)d_in[0];
  const float* ekv = (const float*)d_in[1];
  float* out = (float*)d_out;
  attn_kernel<<<dim3(512), dim3(256), 0, stream>>>(qkv, ekv, out);
}